// Round 9
// baseline (221.457 us; speedup 1.0000x reference)
//
#include <hip/hip_runtime.h>
#include <hip/hip_bf16.h>

#define NN 50000
#define NE 800000
#define D 128
#define DOUT 64
#define PAD 64     // slots per node; P(deg>=64) ~ 2e-18 for Poisson(16)
#define BSH 8      // nodes per bucket = 256
#define NBUCK 196  // ceil(50000/256)
#define CAP 4608   // bucket capacity: mean 4096 + 8 sigma
#define CHUNK 2048 // edges per bin_edges block

typedef __attribute__((ext_vector_type(8))) short short8;
typedef __attribute__((ext_vector_type(4))) float float4v;

// ---------------- bf16 helpers ----------------

__device__ inline unsigned short f2bf(float f) {
    union { float f; unsigned int i; } c; c.f = f;
    unsigned int u = c.i;
    return (unsigned short)((u + 0x7fffu + ((u >> 16) & 1u)) >> 16);  // RNE
}
__device__ inline float bflo(unsigned int u) {
    union { unsigned int i; float f; } c; c.i = u << 16; return c.f;
}
__device__ inline float bfhi(unsigned int u) {
    union { unsigned int i; float f; } c; c.i = u & 0xffff0000u; return c.f;
}

// ---------------- cast x -> bf16 ----------------

__global__ void cast_f32_bf16(const float* __restrict__ in, unsigned short* __restrict__ outb, int n8) {
    int i = blockIdx.x * 256 + threadIdx.x;
    if (i >= n8) return;
    const float4* p = (const float4*)in + (size_t)i * 2;
    float4 a = p[0], b = p[1];
    unsigned int w0 = f2bf(a.x) | ((unsigned int)f2bf(a.y) << 16);
    unsigned int w1 = f2bf(a.z) | ((unsigned int)f2bf(a.w) << 16);
    unsigned int w2 = f2bf(b.x) | ((unsigned int)f2bf(b.y) << 16);
    unsigned int w3 = f2bf(b.z) | ((unsigned int)f2bf(b.w) << 16);
    *(uint4*)(outb + (size_t)i * 8) = make_uint4(w0, w1, w2, w3);
}

// ---------------- pack ALL weights -> bf16 B-fragment order (+ zero gcur) ----------------

struct PackArgs {
    const float* W[5];
    unsigned short* P[5];
    int* gcur;
};

__global__ void pack_all(PackArgs args) {
    if (blockIdx.x == 36) {  // extra block: zero the bucket cursors
        if (threadIdx.x < NBUCK) args.gcur[threadIdx.x] = 0;
        return;
    }
    int idx = blockIdx.x * 256 + threadIdx.x;
    if (idx >= 4 * 2048 + 1024) return;
    const float* W;
    unsigned short* P;
    int COLS, local;
    if (idx < 4 * 2048) {
        int wsel = idx >> 11;
        W = args.W[wsel]; P = args.P[wsel]; COLS = 128; local = idx & 2047;
    } else {
        W = args.W[4]; P = args.P[4]; COLS = 64; local = idx - 4 * 2048;
    }
    int CT = COLS >> 4;
    int lane = local & 63;
    int fi = local >> 6;
    int ct = fi % CT;
    int kstep = fi / CT;
    int krow = kstep * 32 + (lane >> 4) * 8;
    int col = ct * 16 + (lane & 15);
    unsigned short v[8];
#pragma unroll
    for (int j = 0; j < 8; ++j) v[j] = f2bf(W[(size_t)(krow + j) * COLS + col]);
    unsigned int w0 = v[0] | ((unsigned int)v[1] << 16);
    unsigned int w1 = v[2] | ((unsigned int)v[3] << 16);
    unsigned int w2 = v[4] | ((unsigned int)v[5] << 16);
    unsigned int w3 = v[6] | ((unsigned int)v[7] << 16);
    *(uint4*)(P + (size_t)local * 8) = make_uint4(w0, w1, w2, w3);
}

// ---------------- pass 1: block counting-sort of edges into dst buckets ----------------
// record = (dst<<16)|src  (both < 65536); bucket = rec>>24 = dst>>8.

__global__ void bin_edges(const int* __restrict__ src, const int* __restrict__ dst,
                          int* __restrict__ gcur, unsigned int* __restrict__ binned, int e) {
    __shared__ int cnt[NBUCK];
    __shared__ int sh[256];
    __shared__ int baseg[NBUCK];
    __shared__ int lcur[NBUCK];
    __shared__ unsigned int buf[CHUNK];
    int tid = threadIdx.x;
    int base = blockIdx.x * CHUNK;
    for (int b = tid; b < NBUCK; b += 256) cnt[b] = 0;
    __syncthreads();
    unsigned int rec[8];
#pragma unroll
    for (int i = 0; i < 8; ++i) {
        int ei = base + i * 256 + tid;
        rec[i] = 0xffffffffu;
        if (ei < e) {
            unsigned int d = (unsigned int)dst[ei];
            unsigned int s = (unsigned int)src[ei];
            rec[i] = (d << 16) | s;
            atomicAdd(&cnt[d >> BSH], 1);
        }
    }
    __syncthreads();
    int v = (tid < NBUCK) ? cnt[tid] : 0;
    sh[tid] = v;
    __syncthreads();
    for (int off = 1; off < 256; off <<= 1) {
        int t = (tid >= off) ? sh[tid - off] : 0;
        __syncthreads();
        sh[tid] += t;
        __syncthreads();
    }
    if (tid < NBUCK) {
        baseg[tid] = atomicAdd(&gcur[tid], cnt[tid]);
        lcur[tid] = sh[tid] - cnt[tid];
    }
    __syncthreads();
    int total = sh[255];
#pragma unroll
    for (int i = 0; i < 8; ++i) {
        if (rec[i] != 0xffffffffu) {
            int b = rec[i] >> 24;
            int pos = atomicAdd(&lcur[b], 1);
            buf[pos] = rec[i];
        }
    }
    __syncthreads();
    for (int j = tid; j < total; j += 256) {
        unsigned int r = buf[j];
        int b = r >> 24;
        int gidx = baseg[b] + (j - (sh[b] - cnt[b]));
        if (gidx < CAP) binned[(size_t)b * CAP + gidx] = r;
    }
}

// ---------------- pass 2: per-bucket scatter, LDS cursors, L2-local writes ----------------

__global__ void scatter_bucket(const unsigned int* __restrict__ binned, const int* __restrict__ gcur,
                               unsigned short* __restrict__ eidx_pad, int* __restrict__ cursor) {
    __shared__ int cur[256];
    int b = blockIdx.x;
    int tid = threadIdx.x;
    if (tid < 256) cur[tid] = 0;
    __syncthreads();
    int count = gcur[b];
    if (count > CAP) count = CAP;
    const unsigned int* seg = binned + (size_t)b * CAP;
    for (int j = tid; j < count; j += 512) {
        unsigned int r = seg[j];
        int dl = (r >> 16) & 255;
        int slot = atomicAdd(&cur[dl], 1);
        if (slot < PAD)
            eidx_pad[((size_t)((b << BSH) + dl)) * PAD + slot] = (unsigned short)(r & 0xffffu);
    }
    __syncthreads();
    if (tid < 256) {
        int node = (b << BSH) + tid;
        if (node < NN) cursor[node] = (cur[tid] < PAD) ? cur[tid] : PAD;
    }
}

// ---------------- fused layer: agg-gather + dual MFMA GEMM [+ fused FC] ----------------
// Block = 32 nodes, 256 threads (4 waves). Grid = 1563 blocks -> ~6 blocks/CU,
// ~24 waves/CU co-resident. __launch_bounds__(256,6): VGPR cap 85 -- NO scratch
// spill (round-8 lesson: (512,8) capped at 64 and spilled the gather buffers,
// +47 MB of scratch traffic). Gather: 16 groups x 16 lanes, 2 nodes per group,
// 8 gathers in flight, lane = one 16B column chunk. X (self) operand loaded
// directly from global (L2-hot). MFMA wave tile = 16 rows x 64 cols.
// FUSEFC: h -> As (LDS only), out = h @ Pfc + bfc (fp32).

template <bool FUSEFC>
__global__ __launch_bounds__(256, 6)
void fused_layer(const unsigned short* __restrict__ feat,
                 const int* __restrict__ cursor, const unsigned short* __restrict__ eidx_pad,
                 const unsigned short* __restrict__ Pl, const unsigned short* __restrict__ Pr,
                 const float* __restrict__ bias,
                 const unsigned short* __restrict__ Pfc, const float* __restrict__ bfc,
                 unsigned short* __restrict__ outb, float* __restrict__ outf, int n) {
    __shared__ __align__(16) unsigned short As[32][136];

    int tid = threadIdx.x;
    int row0 = blockIdx.x * 32;

    // gather-aggregate -> As: group g (16 lanes) handles nodes g*2, g*2+1
    {
        int g = tid >> 4;
        int l = tid & 15;
#pragma unroll
        for (int nn = 0; nn < 2; ++nn) {
            int r = g * 2 + nn;
            int node = row0 + r;
            float acc[8] = {0.f, 0.f, 0.f, 0.f, 0.f, 0.f, 0.f, 0.f};
            float di = 1.f;
            if (node < n) {
                int deg = cursor[node];
                di = 1.0f / (float)(deg > 1 ? deg : 1);
                const unsigned short* rowp = eidx_pad + (size_t)node * PAD;
                int p = 0;
                for (; p + 7 < deg; p += 8) {
                    uint4 iv = *(const uint4*)(rowp + p);
                    int s0 = iv.x & 0xffff, s1 = iv.x >> 16;
                    int s2 = iv.y & 0xffff, s3 = iv.y >> 16;
                    int s4 = iv.z & 0xffff, s5 = iv.z >> 16;
                    int s6 = iv.w & 0xffff, s7 = iv.w >> 16;
                    uint4 v0 = *(const uint4*)(feat + (size_t)s0 * D + l * 8);
                    uint4 v1 = *(const uint4*)(feat + (size_t)s1 * D + l * 8);
                    uint4 v2 = *(const uint4*)(feat + (size_t)s2 * D + l * 8);
                    uint4 v3 = *(const uint4*)(feat + (size_t)s3 * D + l * 8);
                    uint4 v4 = *(const uint4*)(feat + (size_t)s4 * D + l * 8);
                    uint4 v5 = *(const uint4*)(feat + (size_t)s5 * D + l * 8);
                    uint4 v6 = *(const uint4*)(feat + (size_t)s6 * D + l * 8);
                    uint4 v7 = *(const uint4*)(feat + (size_t)s7 * D + l * 8);
                    acc[0] += ((bflo(v0.x) + bflo(v1.x)) + (bflo(v2.x) + bflo(v3.x)))
                            + ((bflo(v4.x) + bflo(v5.x)) + (bflo(v6.x) + bflo(v7.x)));
                    acc[1] += ((bfhi(v0.x) + bfhi(v1.x)) + (bfhi(v2.x) + bfhi(v3.x)))
                            + ((bfhi(v4.x) + bfhi(v5.x)) + (bfhi(v6.x) + bfhi(v7.x)));
                    acc[2] += ((bflo(v0.y) + bflo(v1.y)) + (bflo(v2.y) + bflo(v3.y)))
                            + ((bflo(v4.y) + bflo(v5.y)) + (bflo(v6.y) + bflo(v7.y)));
                    acc[3] += ((bfhi(v0.y) + bfhi(v1.y)) + (bfhi(v2.y) + bfhi(v3.y)))
                            + ((bfhi(v4.y) + bfhi(v5.y)) + (bfhi(v6.y) + bfhi(v7.y)));
                    acc[4] += ((bflo(v0.z) + bflo(v1.z)) + (bflo(v2.z) + bflo(v3.z)))
                            + ((bflo(v4.z) + bflo(v5.z)) + (bflo(v6.z) + bflo(v7.z)));
                    acc[5] += ((bfhi(v0.z) + bfhi(v1.z)) + (bfhi(v2.z) + bfhi(v3.z)))
                            + ((bfhi(v4.z) + bfhi(v5.z)) + (bfhi(v6.z) + bfhi(v7.z)));
                    acc[6] += ((bflo(v0.w) + bflo(v1.w)) + (bflo(v2.w) + bflo(v3.w)))
                            + ((bflo(v4.w) + bflo(v5.w)) + (bflo(v6.w) + bflo(v7.w)));
                    acc[7] += ((bfhi(v0.w) + bfhi(v1.w)) + (bfhi(v2.w) + bfhi(v3.w)))
                            + ((bfhi(v4.w) + bfhi(v5.w)) + (bfhi(v6.w) + bfhi(v7.w)));
                }
                if (p + 3 < deg) {
                    uint2 iv = *(const uint2*)(rowp + p);
                    int s0 = iv.x & 0xffff, s1 = iv.x >> 16;
                    int s2 = iv.y & 0xffff, s3 = iv.y >> 16;
                    uint4 v0 = *(const uint4*)(feat + (size_t)s0 * D + l * 8);
                    uint4 v1 = *(const uint4*)(feat + (size_t)s1 * D + l * 8);
                    uint4 v2 = *(const uint4*)(feat + (size_t)s2 * D + l * 8);
                    uint4 v3 = *(const uint4*)(feat + (size_t)s3 * D + l * 8);
                    acc[0] += (bflo(v0.x) + bflo(v1.x)) + (bflo(v2.x) + bflo(v3.x));
                    acc[1] += (bfhi(v0.x) + bfhi(v1.x)) + (bfhi(v2.x) + bfhi(v3.x));
                    acc[2] += (bflo(v0.y) + bflo(v1.y)) + (bflo(v2.y) + bflo(v3.y));
                    acc[3] += (bfhi(v0.y) + bfhi(v1.y)) + (bfhi(v2.y) + bfhi(v3.y));
                    acc[4] += (bflo(v0.z) + bflo(v1.z)) + (bflo(v2.z) + bflo(v3.z));
                    acc[5] += (bfhi(v0.z) + bfhi(v1.z)) + (bfhi(v2.z) + bfhi(v3.z));
                    acc[6] += (bflo(v0.w) + bflo(v1.w)) + (bflo(v2.w) + bflo(v3.w));
                    acc[7] += (bfhi(v0.w) + bfhi(v1.w)) + (bfhi(v2.w) + bfhi(v3.w));
                    p += 4;
                }
                for (; p < deg; ++p) {
                    int s = rowp[p];
                    uint4 v0 = *(const uint4*)(feat + (size_t)s * D + l * 8);
                    acc[0] += bflo(v0.x); acc[1] += bfhi(v0.x);
                    acc[2] += bflo(v0.y); acc[3] += bfhi(v0.y);
                    acc[4] += bflo(v0.z); acc[5] += bfhi(v0.z);
                    acc[6] += bflo(v0.w); acc[7] += bfhi(v0.w);
                }
            }
            unsigned int w0 = f2bf(acc[0] * di) | ((unsigned int)f2bf(acc[1] * di) << 16);
            unsigned int w1 = f2bf(acc[2] * di) | ((unsigned int)f2bf(acc[3] * di) << 16);
            unsigned int w2 = f2bf(acc[4] * di) | ((unsigned int)f2bf(acc[5] * di) << 16);
            unsigned int w3 = f2bf(acc[6] * di) | ((unsigned int)f2bf(acc[7] * di) << 16);
            *(uint4*)&As[r][l * 8] = make_uint4(w0, w1, w2, w3);
        }
    }
    __syncthreads();

    int wave = tid >> 6;           // 0..3
    int lane = tid & 63;
    int m16 = lane & 15;
    int quad = lane >> 4;
    int rt0 = (wave & 1) * 16;     // row tile base (2 row tiles of 16)
    int ctb = (wave >> 1) * 4;     // col tile base (2 col halves x 4 tiles)

    float4v acc[4];
#pragma unroll
    for (int c = 0; c < 4; ++c) acc[c] = (float4v){0.f, 0.f, 0.f, 0.f};

    // A-operand pass (aggregated, from LDS)
#pragma unroll
    for (int ks = 0; ks < 4; ++ks) {
        short8 af = *(const short8*)&As[rt0 + m16][ks * 32 + quad * 8];
#pragma unroll
        for (int c = 0; c < 4; ++c) {
            short8 bf = *(const short8*)(Pl + ((size_t)((ks * 8 + ctb + c) * 64 + lane)) * 8);
            acc[c] = __builtin_amdgcn_mfma_f32_16x16x32_bf16(af, bf, acc[c], 0, 0, 0);
        }
    }
    // X-operand pass (self rows, direct from global; L2-hot)
#pragma unroll
    for (int ks = 0; ks < 4; ++ks) {
        int row = row0 + rt0 + m16;
        short8 z = {0, 0, 0, 0, 0, 0, 0, 0};
        short8 xf = (row < n) ? *(const short8*)(feat + (size_t)row * D + ks * 32 + quad * 8) : z;
#pragma unroll
        for (int c = 0; c < 4; ++c) {
            short8 bf = *(const short8*)(Pr + ((size_t)((ks * 8 + ctb + c) * 64 + lane)) * 8);
            acc[c] = __builtin_amdgcn_mfma_f32_16x16x32_bf16(xf, bf, acc[c], 0, 0, 0);
        }
    }

    if (!FUSEFC) {
#pragma unroll
        for (int c = 0; c < 4; ++c) {
            int col = (ctb + c) * 16 + m16;
            float bv = bias[col];
#pragma unroll
            for (int i = 0; i < 4; ++i) {
                int row = row0 + rt0 + quad * 4 + i;
                if (row < n)
                    outb[(size_t)row * D + col] = f2bf(fmaxf(acc[c][i] + bv, 0.f));
            }
        }
    } else {
        __syncthreads();
#pragma unroll
        for (int c = 0; c < 4; ++c) {
            int col = (ctb + c) * 16 + m16;
            float bv = bias[col];
#pragma unroll
            for (int i = 0; i < 4; ++i) {
                int row = rt0 + quad * 4 + i;
                As[row][col] = f2bf(fmaxf(acc[c][i] + bv, 0.f));
            }
        }
        __syncthreads();

        int ctbF = (wave >> 1) * 2;   // col tiles {0,1} or {2,3} -> cols 0-31 / 32-63
        float4v acc2[2];
#pragma unroll
        for (int c = 0; c < 2; ++c) acc2[c] = (float4v){0.f, 0.f, 0.f, 0.f};
#pragma unroll
        for (int ks = 0; ks < 4; ++ks) {
            short8 hf = *(const short8*)&As[rt0 + m16][ks * 32 + quad * 8];
#pragma unroll
            for (int c = 0; c < 2; ++c) {
                short8 bf = *(const short8*)(Pfc + ((size_t)((ks * 4 + ctbF + c) * 64 + lane)) * 8);
                acc2[c] = __builtin_amdgcn_mfma_f32_16x16x32_bf16(hf, bf, acc2[c], 0, 0, 0);
            }
        }
#pragma unroll
        for (int c = 0; c < 2; ++c) {
            int col = (ctbF + c) * 16 + m16;
            float bv = bfc[col];
#pragma unroll
            for (int i = 0; i < 4; ++i) {
                int row = row0 + rt0 + quad * 4 + i;
                if (row < n)
                    outf[(size_t)row * DOUT + col] = acc2[c][i] + bv;
            }
        }
    }
}

// ---------------- launch ----------------

extern "C" void kernel_launch(void* const* d_in, const int* in_sizes, int n_in,
                              void* d_out, int out_size, void* d_ws, size_t ws_size,
                              hipStream_t stream) {
    const float* x   = (const float*)d_in[0];
    const int*   ei  = (const int*)d_in[1];
    const float* Wl0 = (const float*)d_in[2];
    const float* Wr0 = (const float*)d_in[3];
    const float* b0  = (const float*)d_in[4];
    const float* Wl1 = (const float*)d_in[5];
    const float* Wr1 = (const float*)d_in[6];
    const float* b1  = (const float*)d_in[7];
    const float* Wfc = (const float*)d_in[8];
    const float* bfc = (const float*)d_in[9];
    float* out = (float*)d_out;

    const int* src = ei;
    const int* dst = ei + NE;

    char* p = (char*)d_ws;
    auto carve = [&](size_t bytes) {
        char* q = p;
        p += (bytes + 255) & ~(size_t)255;
        return q;
    };
    int*            cursor   = (int*)carve(NN * sizeof(int));
    int*            gcur     = (int*)carve(NBUCK * sizeof(int));
    unsigned int*   binned   = (unsigned int*)carve((size_t)NBUCK * CAP * 4);
    unsigned short* eidx_pad = (unsigned short*)carve((size_t)NN * PAD * 2);
    unsigned short* xb   = (unsigned short*)carve((size_t)NN * D * 2);
    unsigned short* h0b  = (unsigned short*)carve((size_t)NN * D * 2);
    unsigned short* Wl0p = (unsigned short*)carve(D * D * 2);
    unsigned short* Wr0p = (unsigned short*)carve(D * D * 2);
    unsigned short* Wl1p = (unsigned short*)carve(D * D * 2);
    unsigned short* Wr1p = (unsigned short*)carve(D * D * 2);
    unsigned short* Wfcp = (unsigned short*)carve(D * DOUT * 2);

    const int N8 = NN * D / 8;
    cast_f32_bf16<<<(N8 + 255) / 256, 256, 0, stream>>>(x, xb, N8);

    PackArgs pa;
    pa.W[0] = Wl0; pa.W[1] = Wr0; pa.W[2] = Wl1; pa.W[3] = Wr1; pa.W[4] = Wfc;
    pa.P[0] = Wl0p; pa.P[1] = Wr0p; pa.P[2] = Wl1p; pa.P[3] = Wr1p; pa.P[4] = Wfcp;
    pa.gcur = gcur;
    pack_all<<<37, 256, 0, stream>>>(pa);   // block 36 zeroes gcur

    const int BINB = (NE + CHUNK - 1) / CHUNK;   // 391
    bin_edges<<<BINB, 256, 0, stream>>>(src, dst, gcur, binned, NE);
    scatter_bucket<<<NBUCK, 512, 0, stream>>>(binned, gcur, eidx_pad, cursor);

    const int GB = (NN + 31) / 32;   // 1563 blocks -> ~6 blocks/CU

    // layer 0: h0 = relu(agg(xb)@Wl0 + xb@Wr0 + b0)
    fused_layer<false><<<GB, 256, 0, stream>>>(xb, cursor, eidx_pad, Wl0p, Wr0p, b0,
                                               nullptr, nullptr, h0b, nullptr, NN);
    // layer 1 + FC: out = (relu(agg(h0)@Wl1 + h0@Wr1 + b1)) @ Wfc + bfc
    fused_layer<true><<<GB, 256, 0, stream>>>(h0b, cursor, eidx_pad, Wl1p, Wr1p, b1,
                                              Wfcp, bfc, nullptr, out, NN);
}

// Round 10
// 197.426 us; speedup vs baseline: 1.1217x; 1.1217x over previous
//
#include <hip/hip_runtime.h>
#include <hip/hip_bf16.h>

#define NN 50000
#define NE 800000
#define D 128
#define DOUT 64
#define PAD 64     // slots per node; P(deg>=64) ~ 2e-18 for Poisson(16)
#define BSH 8      // nodes per bucket = 256
#define NBUCK 196  // ceil(50000/256)
#define CAP 4608   // bucket capacity: mean 4096 + 8 sigma
#define CHUNK 4096 // edges per bin_edges block (196 blocks)
#define N8 (NN * D / 8)

typedef __attribute__((ext_vector_type(8))) short short8;
typedef __attribute__((ext_vector_type(4))) float float4v;

// ---------------- bf16 helpers ----------------

__device__ inline unsigned short f2bf(float f) {
    union { float f; unsigned int i; } c; c.f = f;
    unsigned int u = c.i;
    return (unsigned short)((u + 0x7fffu + ((u >> 16) & 1u)) >> 16);  // RNE
}
__device__ inline float bflo(unsigned int u) {
    union { unsigned int i; float f; } c; c.i = u << 16; return c.f;
}
__device__ inline float bfhi(unsigned int u) {
    union { unsigned int i; float f; } c; c.i = u & 0xffff0000u; return c.f;
}

// ---------------- prep: cast x->bf16 + pack all weights + zero gcur (ONE launch) ----
// blocks 0..35  : pack jobs (36*256 = 9216 = 4*2048 + 1024 exactly)
// block  36     : zero gcur
// blocks 37..255: grid-stride cast of x (800000 16B-chunks)

struct PrepArgs {
    const float* W[5];
    unsigned short* P[5];
    int* gcur;
    const float* x;
    unsigned short* xb;
};

__global__ void prep(PrepArgs args) {
    int b = blockIdx.x;
    if (b < 36) {
        int idx = b * 256 + threadIdx.x;   // 0..9215
        const float* W;
        unsigned short* P;
        int COLS, local;
        if (idx < 4 * 2048) {
            int wsel = idx >> 11;
            W = args.W[wsel]; P = args.P[wsel]; COLS = 128; local = idx & 2047;
        } else {
            W = args.W[4]; P = args.P[4]; COLS = 64; local = idx - 4 * 2048;
        }
        int CT = COLS >> 4;
        int lane = local & 63;
        int fi = local >> 6;
        int ct = fi % CT;
        int kstep = fi / CT;
        int krow = kstep * 32 + (lane >> 4) * 8;
        int col = ct * 16 + (lane & 15);
        unsigned short v[8];
#pragma unroll
        for (int j = 0; j < 8; ++j) v[j] = f2bf(W[(size_t)(krow + j) * COLS + col]);
        unsigned int w0 = v[0] | ((unsigned int)v[1] << 16);
        unsigned int w1 = v[2] | ((unsigned int)v[3] << 16);
        unsigned int w2 = v[4] | ((unsigned int)v[5] << 16);
        unsigned int w3 = v[6] | ((unsigned int)v[7] << 16);
        *(uint4*)(P + (size_t)local * 8) = make_uint4(w0, w1, w2, w3);
    } else if (b == 36) {
        if (threadIdx.x < NBUCK) args.gcur[threadIdx.x] = 0;
    } else {
        int stride = (gridDim.x - 37) * 256;
        for (int i = (b - 37) * 256 + threadIdx.x; i < N8; i += stride) {
            const float4* p = (const float4*)args.x + (size_t)i * 2;
            float4 a = p[0], bb = p[1];
            unsigned int w0 = f2bf(a.x) | ((unsigned int)f2bf(a.y) << 16);
            unsigned int w1 = f2bf(a.z) | ((unsigned int)f2bf(a.w) << 16);
            unsigned int w2 = f2bf(bb.x) | ((unsigned int)f2bf(bb.y) << 16);
            unsigned int w3 = f2bf(bb.z) | ((unsigned int)f2bf(bb.w) << 16);
            *(uint4*)(args.xb + (size_t)i * 8) = make_uint4(w0, w1, w2, w3);
        }
    }
}

// ---------------- pass 1: block counting-sort of edges into dst buckets ----------------
// record = (dst<<16)|src  (both < 65536); bucket = rec>>24 = dst>>8.

__global__ void bin_edges(const int* __restrict__ src, const int* __restrict__ dst,
                          int* __restrict__ gcur, unsigned int* __restrict__ binned, int e) {
    __shared__ int cnt[NBUCK];
    __shared__ int sh[256];
    __shared__ int baseg[NBUCK];
    __shared__ int lcur[NBUCK];
    __shared__ unsigned int buf[CHUNK];
    int tid = threadIdx.x;
    int base = blockIdx.x * CHUNK;
    for (int b = tid; b < NBUCK; b += 256) cnt[b] = 0;
    __syncthreads();
    unsigned int rec[16];
#pragma unroll
    for (int i = 0; i < 16; ++i) {
        int ei = base + i * 256 + tid;
        rec[i] = 0xffffffffu;
        if (ei < e) {
            unsigned int d = (unsigned int)dst[ei];
            unsigned int s = (unsigned int)src[ei];
            rec[i] = (d << 16) | s;
            atomicAdd(&cnt[d >> BSH], 1);
        }
    }
    __syncthreads();
    int v = (tid < NBUCK) ? cnt[tid] : 0;
    sh[tid] = v;
    __syncthreads();
    for (int off = 1; off < 256; off <<= 1) {
        int t = (tid >= off) ? sh[tid - off] : 0;
        __syncthreads();
        sh[tid] += t;
        __syncthreads();
    }
    if (tid < NBUCK) {
        baseg[tid] = atomicAdd(&gcur[tid], cnt[tid]);
        lcur[tid] = sh[tid] - cnt[tid];
    }
    __syncthreads();
    int total = sh[255];
#pragma unroll
    for (int i = 0; i < 16; ++i) {
        if (rec[i] != 0xffffffffu) {
            int b = rec[i] >> 24;
            int pos = atomicAdd(&lcur[b], 1);
            buf[pos] = rec[i];
        }
    }
    __syncthreads();
    for (int j = tid; j < total; j += 256) {
        unsigned int r = buf[j];
        int b = r >> 24;
        int gidx = baseg[b] + (j - (sh[b] - cnt[b]));
        if (gidx < CAP) binned[(size_t)b * CAP + gidx] = r;
    }
}

// ---------------- pass 2: per-bucket scatter, LDS cursors, L2-local writes ----------------

__global__ void scatter_bucket(const unsigned int* __restrict__ binned, const int* __restrict__ gcur,
                               unsigned short* __restrict__ eidx_pad, int* __restrict__ cursor) {
    __shared__ int cur[256];
    int b = blockIdx.x;
    int tid = threadIdx.x;
    if (tid < 256) cur[tid] = 0;
    __syncthreads();
    int count = gcur[b];
    if (count > CAP) count = CAP;
    const unsigned int* seg = binned + (size_t)b * CAP;
    for (int j = tid; j < count; j += 512) {
        unsigned int r = seg[j];
        int dl = (r >> 16) & 255;
        int slot = atomicAdd(&cur[dl], 1);
        if (slot < PAD)
            eidx_pad[((size_t)((b << BSH) + dl)) * PAD + slot] = (unsigned short)(r & 0xffffu);
    }
    __syncthreads();
    if (tid < 256) {
        int node = (b << BSH) + tid;
        if (node < NN) cursor[node] = (cur[tid] < PAD) ? cur[tid] : PAD;
    }
}

// ---------------- fused layer: agg-gather + dual MFMA GEMM [+ fused FC] ----------------
// EXACT r7 config (proven local optimum): block = 64 nodes, 256 threads,
// __launch_bounds__(256,4) -> VGPR 48, no spill. Gather: 16 groups x 16 lanes,
// 2 nodes per group, 8 gathers in flight, lane = one 16B column chunk.
// X (self) operand loaded directly from global (L2-hot). No Xs LDS tile.
// FUSEFC: h -> As (LDS only), out = h @ Pfc + bfc (fp32).
// NOTE (r8/r9 lesson): do NOT raise waves via launch_bounds or smaller tiles —
// (512,8) and (256,6) both spilled the gather buffers to scratch (+20-47 MB
// FETCH/WRITE); 32-node tiles raise the instantaneous working set -> FETCH 81->97 MB.

template <bool FUSEFC>
__global__ __launch_bounds__(256, 4)
void fused_layer(const unsigned short* __restrict__ feat,
                 const int* __restrict__ cursor, const unsigned short* __restrict__ eidx_pad,
                 const unsigned short* __restrict__ Pl, const unsigned short* __restrict__ Pr,
                 const float* __restrict__ bias,
                 const unsigned short* __restrict__ Pfc, const float* __restrict__ bfc,
                 unsigned short* __restrict__ outb, float* __restrict__ outf, int n) {
    __shared__ __align__(16) unsigned short As[64][136];

    int tid = threadIdx.x;
    int row0 = blockIdx.x * 64;

    // gather-aggregate -> As: group g (16 lanes) handles nodes g*2, g*2+1... wait,
    // r7 layout: 16 groups x 16 lanes, 4 nodes per group (g*4..g*4+3)
    {
        int g = tid >> 4;
        int l = tid & 15;
#pragma unroll
        for (int nn = 0; nn < 4; ++nn) {
            int r = g * 4 + nn;
            int node = row0 + r;
            float acc[8] = {0.f, 0.f, 0.f, 0.f, 0.f, 0.f, 0.f, 0.f};
            float di = 1.f;
            if (node < n) {
                int deg = cursor[node];
                di = 1.0f / (float)(deg > 1 ? deg : 1);
                const unsigned short* rowp = eidx_pad + (size_t)node * PAD;
                int p = 0;
                for (; p + 7 < deg; p += 8) {
                    uint4 iv = *(const uint4*)(rowp + p);
                    int s0 = iv.x & 0xffff, s1 = iv.x >> 16;
                    int s2 = iv.y & 0xffff, s3 = iv.y >> 16;
                    int s4 = iv.z & 0xffff, s5 = iv.z >> 16;
                    int s6 = iv.w & 0xffff, s7 = iv.w >> 16;
                    uint4 v0 = *(const uint4*)(feat + (size_t)s0 * D + l * 8);
                    uint4 v1 = *(const uint4*)(feat + (size_t)s1 * D + l * 8);
                    uint4 v2 = *(const uint4*)(feat + (size_t)s2 * D + l * 8);
                    uint4 v3 = *(const uint4*)(feat + (size_t)s3 * D + l * 8);
                    uint4 v4 = *(const uint4*)(feat + (size_t)s4 * D + l * 8);
                    uint4 v5 = *(const uint4*)(feat + (size_t)s5 * D + l * 8);
                    uint4 v6 = *(const uint4*)(feat + (size_t)s6 * D + l * 8);
                    uint4 v7 = *(const uint4*)(feat + (size_t)s7 * D + l * 8);
                    acc[0] += ((bflo(v0.x) + bflo(v1.x)) + (bflo(v2.x) + bflo(v3.x)))
                            + ((bflo(v4.x) + bflo(v5.x)) + (bflo(v6.x) + bflo(v7.x)));
                    acc[1] += ((bfhi(v0.x) + bfhi(v1.x)) + (bfhi(v2.x) + bfhi(v3.x)))
                            + ((bfhi(v4.x) + bfhi(v5.x)) + (bfhi(v6.x) + bfhi(v7.x)));
                    acc[2] += ((bflo(v0.y) + bflo(v1.y)) + (bflo(v2.y) + bflo(v3.y)))
                            + ((bflo(v4.y) + bflo(v5.y)) + (bflo(v6.y) + bflo(v7.y)));
                    acc[3] += ((bfhi(v0.y) + bfhi(v1.y)) + (bfhi(v2.y) + bfhi(v3.y)))
                            + ((bfhi(v4.y) + bfhi(v5.y)) + (bfhi(v6.y) + bfhi(v7.y)));
                    acc[4] += ((bflo(v0.z) + bflo(v1.z)) + (bflo(v2.z) + bflo(v3.z)))
                            + ((bflo(v4.z) + bflo(v5.z)) + (bflo(v6.z) + bflo(v7.z)));
                    acc[5] += ((bfhi(v0.z) + bfhi(v1.z)) + (bfhi(v2.z) + bfhi(v3.z)))
                            + ((bfhi(v4.z) + bfhi(v5.z)) + (bfhi(v6.z) + bfhi(v7.z)));
                    acc[6] += ((bflo(v0.w) + bflo(v1.w)) + (bflo(v2.w) + bflo(v3.w)))
                            + ((bflo(v4.w) + bflo(v5.w)) + (bflo(v6.w) + bflo(v7.w)));
                    acc[7] += ((bfhi(v0.w) + bfhi(v1.w)) + (bfhi(v2.w) + bfhi(v3.w)))
                            + ((bfhi(v4.w) + bfhi(v5.w)) + (bfhi(v6.w) + bfhi(v7.w)));
                }
                if (p + 3 < deg) {
                    uint2 iv = *(const uint2*)(rowp + p);
                    int s0 = iv.x & 0xffff, s1 = iv.x >> 16;
                    int s2 = iv.y & 0xffff, s3 = iv.y >> 16;
                    uint4 v0 = *(const uint4*)(feat + (size_t)s0 * D + l * 8);
                    uint4 v1 = *(const uint4*)(feat + (size_t)s1 * D + l * 8);
                    uint4 v2 = *(const uint4*)(feat + (size_t)s2 * D + l * 8);
                    uint4 v3 = *(const uint4*)(feat + (size_t)s3 * D + l * 8);
                    acc[0] += (bflo(v0.x) + bflo(v1.x)) + (bflo(v2.x) + bflo(v3.x));
                    acc[1] += (bfhi(v0.x) + bfhi(v1.x)) + (bfhi(v2.x) + bfhi(v3.x));
                    acc[2] += (bflo(v0.y) + bflo(v1.y)) + (bflo(v2.y) + bflo(v3.y));
                    acc[3] += (bfhi(v0.y) + bfhi(v1.y)) + (bfhi(v2.y) + bfhi(v3.y));
                    acc[4] += (bflo(v0.z) + bflo(v1.z)) + (bflo(v2.z) + bflo(v3.z));
                    acc[5] += (bfhi(v0.z) + bfhi(v1.z)) + (bfhi(v2.z) + bfhi(v3.z));
                    acc[6] += (bflo(v0.w) + bflo(v1.w)) + (bflo(v2.w) + bflo(v3.w));
                    acc[7] += (bfhi(v0.w) + bfhi(v1.w)) + (bfhi(v2.w) + bfhi(v3.w));
                    p += 4;
                }
                for (; p < deg; ++p) {
                    int s = rowp[p];
                    uint4 v0 = *(const uint4*)(feat + (size_t)s * D + l * 8);
                    acc[0] += bflo(v0.x); acc[1] += bfhi(v0.x);
                    acc[2] += bflo(v0.y); acc[3] += bfhi(v0.y);
                    acc[4] += bflo(v0.z); acc[5] += bfhi(v0.z);
                    acc[6] += bflo(v0.w); acc[7] += bfhi(v0.w);
                }
            }
            unsigned int w0 = f2bf(acc[0] * di) | ((unsigned int)f2bf(acc[1] * di) << 16);
            unsigned int w1 = f2bf(acc[2] * di) | ((unsigned int)f2bf(acc[3] * di) << 16);
            unsigned int w2 = f2bf(acc[4] * di) | ((unsigned int)f2bf(acc[5] * di) << 16);
            unsigned int w3 = f2bf(acc[6] * di) | ((unsigned int)f2bf(acc[7] * di) << 16);
            *(uint4*)&As[r][l * 8] = make_uint4(w0, w1, w2, w3);
        }
    }
    __syncthreads();

    int wave = tid >> 6;
    int lane = tid & 63;
    int m16 = lane & 15;
    int quad = lane >> 4;
    int rt0 = (wave & 1) * 32;
    int ctb = (wave >> 1) * 4;

    float4v acc[2][4];
#pragma unroll
    for (int t = 0; t < 2; ++t)
#pragma unroll
        for (int c = 0; c < 4; ++c) acc[t][c] = (float4v){0.f, 0.f, 0.f, 0.f};

    // A-operand pass (aggregated, from LDS)
#pragma unroll
    for (int ks = 0; ks < 4; ++ks) {
        short8 af[2];
#pragma unroll
        for (int t = 0; t < 2; ++t)
            af[t] = *(const short8*)&As[rt0 + t * 16 + m16][ks * 32 + quad * 8];
#pragma unroll
        for (int c = 0; c < 4; ++c) {
            short8 bf = *(const short8*)(Pl + ((size_t)((ks * 8 + ctb + c) * 64 + lane)) * 8);
#pragma unroll
            for (int t = 0; t < 2; ++t)
                acc[t][c] = __builtin_amdgcn_mfma_f32_16x16x32_bf16(af[t], bf, acc[t][c], 0, 0, 0);
        }
    }
    // X-operand pass (self rows, direct from global; L2-hot)
#pragma unroll
    for (int ks = 0; ks < 4; ++ks) {
        short8 xf[2];
#pragma unroll
        for (int t = 0; t < 2; ++t) {
            int row = row0 + rt0 + t * 16 + m16;
            short8 z = {0, 0, 0, 0, 0, 0, 0, 0};
            xf[t] = (row < n) ? *(const short8*)(feat + (size_t)row * D + ks * 32 + quad * 8) : z;
        }
#pragma unroll
        for (int c = 0; c < 4; ++c) {
            short8 bf = *(const short8*)(Pr + ((size_t)((ks * 8 + ctb + c) * 64 + lane)) * 8);
#pragma unroll
            for (int t = 0; t < 2; ++t)
                acc[t][c] = __builtin_amdgcn_mfma_f32_16x16x32_bf16(xf[t], bf, acc[t][c], 0, 0, 0);
        }
    }

    if (!FUSEFC) {
#pragma unroll
        for (int t = 0; t < 2; ++t) {
#pragma unroll
            for (int c = 0; c < 4; ++c) {
                int col = (ctb + c) * 16 + m16;
                float bv = bias[col];
#pragma unroll
                for (int i = 0; i < 4; ++i) {
                    int row = row0 + rt0 + t * 16 + quad * 4 + i;
                    if (row < n)
                        outb[(size_t)row * D + col] = f2bf(fmaxf(acc[t][c][i] + bv, 0.f));
                }
            }
        }
    } else {
        __syncthreads();
#pragma unroll
        for (int t = 0; t < 2; ++t) {
#pragma unroll
            for (int c = 0; c < 4; ++c) {
                int col = (ctb + c) * 16 + m16;
                float bv = bias[col];
#pragma unroll
                for (int i = 0; i < 4; ++i) {
                    int row = rt0 + t * 16 + quad * 4 + i;
                    As[row][col] = f2bf(fmaxf(acc[t][c][i] + bv, 0.f));
                }
            }
        }
        __syncthreads();

        int ctbF = (wave >> 1) * 2;
        float4v acc2[2][2];
#pragma unroll
        for (int t = 0; t < 2; ++t)
#pragma unroll
            for (int c = 0; c < 2; ++c) acc2[t][c] = (float4v){0.f, 0.f, 0.f, 0.f};
#pragma unroll
        for (int ks = 0; ks < 4; ++ks) {
            short8 hf[2];
#pragma unroll
            for (int t = 0; t < 2; ++t)
                hf[t] = *(const short8*)&As[rt0 + t * 16 + m16][ks * 32 + quad * 8];
#pragma unroll
            for (int c = 0; c < 2; ++c) {
                short8 bf = *(const short8*)(Pfc + ((size_t)((ks * 4 + ctbF + c) * 64 + lane)) * 8);
#pragma unroll
                for (int t = 0; t < 2; ++t)
                    acc2[t][c] = __builtin_amdgcn_mfma_f32_16x16x32_bf16(hf[t], bf, acc2[t][c], 0, 0, 0);
            }
        }
#pragma unroll
        for (int t = 0; t < 2; ++t) {
#pragma unroll
            for (int c = 0; c < 2; ++c) {
                int col = (ctbF + c) * 16 + m16;
                float bv = bfc[col];
#pragma unroll
                for (int i = 0; i < 4; ++i) {
                    int row = row0 + rt0 + t * 16 + quad * 4 + i;
                    if (row < n)
                        outf[(size_t)row * DOUT + col] = acc2[t][c][i] + bv;
                }
            }
        }
    }
}

// ---------------- launch ----------------

extern "C" void kernel_launch(void* const* d_in, const int* in_sizes, int n_in,
                              void* d_out, int out_size, void* d_ws, size_t ws_size,
                              hipStream_t stream) {
    const float* x   = (const float*)d_in[0];
    const int*   ei  = (const int*)d_in[1];
    const float* Wl0 = (const float*)d_in[2];
    const float* Wr0 = (const float*)d_in[3];
    const float* b0  = (const float*)d_in[4];
    const float* Wl1 = (const float*)d_in[5];
    const float* Wr1 = (const float*)d_in[6];
    const float* b1  = (const float*)d_in[7];
    const float* Wfc = (const float*)d_in[8];
    const float* bfc = (const float*)d_in[9];
    float* out = (float*)d_out;

    const int* src = ei;
    const int* dst = ei + NE;

    char* p = (char*)d_ws;
    auto carve = [&](size_t bytes) {
        char* q = p;
        p += (bytes + 255) & ~(size_t)255;
        return q;
    };
    int*            cursor   = (int*)carve(NN * sizeof(int));
    int*            gcur     = (int*)carve(NBUCK * sizeof(int));
    unsigned int*   binned   = (unsigned int*)carve((size_t)NBUCK * CAP * 4);
    unsigned short* eidx_pad = (unsigned short*)carve((size_t)NN * PAD * 2);
    unsigned short* xb   = (unsigned short*)carve((size_t)NN * D * 2);
    unsigned short* h0b  = (unsigned short*)carve((size_t)NN * D * 2);
    unsigned short* Wl0p = (unsigned short*)carve(D * D * 2);
    unsigned short* Wr0p = (unsigned short*)carve(D * D * 2);
    unsigned short* Wl1p = (unsigned short*)carve(D * D * 2);
    unsigned short* Wr1p = (unsigned short*)carve(D * D * 2);
    unsigned short* Wfcp = (unsigned short*)carve(D * DOUT * 2);

    PrepArgs pa;
    pa.W[0] = Wl0; pa.W[1] = Wr0; pa.W[2] = Wl1; pa.W[3] = Wr1; pa.W[4] = Wfc;
    pa.P[0] = Wl0p; pa.P[1] = Wr0p; pa.P[2] = Wl1p; pa.P[3] = Wr1p; pa.P[4] = Wfcp;
    pa.gcur = gcur;
    pa.x = x; pa.xb = xb;
    prep<<<256, 256, 0, stream>>>(pa);

    const int BINB = (NE + CHUNK - 1) / CHUNK;   // 196
    bin_edges<<<BINB, 256, 0, stream>>>(src, dst, gcur, binned, NE);
    scatter_bucket<<<NBUCK, 512, 0, stream>>>(binned, gcur, eidx_pad, cursor);

    const int GB = (NN + 63) / 64;   // 782

    // layer 0: h0 = relu(agg(xb)@Wl0 + xb@Wr0 + b0)
    fused_layer<false><<<GB, 256, 0, stream>>>(xb, cursor, eidx_pad, Wl0p, Wr0p, b0,
                                               nullptr, nullptr, h0b, nullptr, NN);
    // layer 1 + FC: out = (relu(agg(h0)@Wl1 + h0@Wr1 + b1)) @ Wfc + bfc
    fused_layer<true><<<GB, 256, 0, stream>>>(h0b, cursor, eidx_pad, Wl1p, Wr1p, b1,
                                              Wfcp, bfc, nullptr, out, NN);
}